// Round 23
// baseline (758.019 us; speedup 1.0000x reference)
//
#include <hip/hip_runtime.h>
#include <hip/hip_bf16.h>

typedef __attribute__((ext_vector_type(8))) short short8;
typedef __attribute__((ext_vector_type(4))) float floatx4;
typedef unsigned short u16;

#define D 256
#define BM 32
#define NT 256
#define NBLK 1024

__device__ __forceinline__ short f2bf(float f) {
    return __builtin_bit_cast(short, __float2bfloat16(f));
}

// prep: blocks [0,256): W1 fp32 [k][n] -> W1F bf16 MFMA-fragment-major:
// W1F[((k0t*16+nt)*64+lane)*8+j] = W1[k0t*32+(lane>>4)*8+j][nt*16+(lane&15)]
//       blocks [256,384): zero d_out.
__global__ void prep_kernel(const float* __restrict__ W1, u16* __restrict__ W1F,
                            float* __restrict__ out, int outn) {
    const int b = blockIdx.x;
    if (b < D) {
        const int k = b, n = threadIdx.x;
        const int k0t = k >> 5, g = (k >> 3) & 3, j = k & 7;
        const int nt = n >> 4, l15 = n & 15;
        W1F[(long)((((k0t << 4) + nt) << 6) + (g << 4) + l15) * 8 + j] = (u16)f2bf(W1[k * D + n]);
    } else {
        int i = (b - D) * 256 + threadIdx.x;
        const int stride = (gridDim.x - D) * 256;
        for (; i < outn; i += stride) out[i] = 0.f;
    }
}

// Persistent pipelined head with RAW s_barrier (no implicit vmcnt(0) drain).
// R22 bug fixed: staging now covers ALL 256 k per tile (thread (arow=tid>>3,
// s8=tid&7) loads groups s8+8j, j=0..3 -> 128B/thread; 256 thr x 128B = 32KB).
// Per iter: {V_st/idx loads + burst prefetch A(t+NBLK), pinned} -> compute(t)
// from LDS -> epilogue -> s_red write -> cvt+ds_write A(t+1) (counted vmcnt
// wait hidden under compute) -> lgkmcnt(0); s_barrier; fence -> scatter.
// The prefetch burst crosses the barrier IN FLIGHT (impossible w/ __syncthreads).
__launch_bounds__(NT, 4)
__global__ void head_kernel(const float* __restrict__ forces,
                            const float* __restrict__ V_st,
                            const u16*   __restrict__ W1F,
                            const float* __restrict__ b1,
                            const float* __restrict__ W2,
                            const float* __restrict__ b2,
                            const int*   __restrict__ idx_t,
                            float* __restrict__ out,
                            int E) {
    // A frag f = k0t*2 + (row>>4); in-frag slot ((g<<4)|(row&15))*8 shorts
    __shared__ u16 Albs[2][16 * 512];   // 2 x 16 KiB, double-buffered
    __shared__ float s_red[2][4][BM];   // 1 KiB, phase-parity buffered

    const int tid  = threadIdx.x;
    const int lane = tid & 63;
    const int wq   = tid >> 6;        // 0..3: col quarter owned by this wave
    const int l15  = lane & 15;
    const int g    = lane >> 4;       // 0..3
    const int ntiles = E / BM;        // 25000 (E%32==0)
    const long b = blockIdx.x;
    const int niter = (int)(((long)ntiles - b + NBLK - 1) / NBLK);

    // staging geometry: thread (arow=tid>>3, s8=tid&7) covers groups s8+8j,
    // j=0..3 (8 floats each). Full coverage: 32 rows x 32 groups.
    const int arow = tid >> 3;        // 0..31
    const int s8   = tid & 7;         // 0..7
    int asl[4];
#pragma unroll
    for (int j = 0; j < 4; ++j) {
        int gp = s8 + 8 * j;
        int f  = (gp >> 2) * 2 + (arow >> 4);
        asl[j] = f * 512 + (((gp & 3) << 4) | (arow & 15)) * 8;
    }

    // per-wave epilogue constants (L1-hot)
    float b1v[4], w2v[4];
#pragma unroll
    for (int nc = 0; nc < 4; ++nc) {
        int n = wq * 64 + nc * 16 + l15;
        b1v[nc] = b1[n];
        w2v[nc] = W2[n];
    }
    const float b2v = b2[0];

    auto LOADA = [&](long tile, floatx4* r0, floatx4* r1) {
        const float* src = forces + (tile * BM + arow) * (long)D;
#pragma unroll
        for (int j = 0; j < 4; ++j) {
            int gp = s8 + 8 * j;
            r0[j] = *(const floatx4*)(src + gp * 8);
            r1[j] = *(const floatx4*)(src + gp * 8 + 4);
        }
    };
    auto CVTW = [&](int buf, const floatx4* r0, const floatx4* r1) {
#pragma unroll
        for (int j = 0; j < 4; ++j) {
            short8 a;
#pragma unroll
            for (int q = 0; q < 4; ++q) { a[q] = f2bf(r0[j][q]); a[4 + q] = f2bf(r1[j][q]); }
            *(short8*)&Albs[buf][asl[j]] = a;
        }
    };

    // ---- prologue: stage tile b into buffer 0 ----
    {
        floatx4 r0[4], r1[4];
        LOADA(b, r0, r1);
        CVTW(0, r0, r1);
    }
    asm volatile("s_waitcnt lgkmcnt(0)" ::: "memory");
    __builtin_amdgcn_s_barrier();
    asm volatile("" ::: "memory");
    __builtin_amdgcn_sched_barrier(0);

    for (int i = 0; i < niter; ++i) {
        const long t   = b + (long)i * NBLK;
        const int  cur = i & 1;
        const bool more = (i + 1) < niter;

        // ---- scatter operands for tile t + burst prefetch A(t+NBLK) ----
        float vx = 0.f, vy = 0.f, vz = 0.f;
        int nd = -1;
        if (tid < BM) {
            long e = t * BM + tid;
            vx = V_st[e * 3 + 0]; vy = V_st[e * 3 + 1]; vz = V_st[e * 3 + 2];
            nd = idx_t[e];
        }
        floatx4 r0[4], r1[4];
        if (more) LOADA(t + NBLK, r0, r1);
        __builtin_amdgcn_sched_barrier(0);   // pin issue: loads may not sink

        // ---- compute tile t from Albs[cur]; wave = 32 rows x 64 cols ----
        floatx4 acc[2][4];
#pragma unroll
        for (int rt = 0; rt < 2; ++rt)
#pragma unroll
            for (int nc = 0; nc < 4; ++nc)
                acc[rt][nc] = (floatx4){0.f, 0.f, 0.f, 0.f};

#pragma unroll
        for (int k0t = 0; k0t < 8; ++k0t) {
            short8 bf[4], af[2];
#pragma unroll
            for (int nc = 0; nc < 4; ++nc)
                bf[nc] = *(const short8*)(W1F + (long)((k0t * 16 + wq * 4 + nc) * 64 + lane) * 8);
#pragma unroll
            for (int rt = 0; rt < 2; ++rt)
                af[rt] = *(const short8*)&Albs[cur][(k0t * 2 + rt) * 512 + lane * 8];
#pragma unroll
            for (int rt = 0; rt < 2; ++rt)
#pragma unroll
                for (int nc = 0; nc < 4; ++nc)
                    acc[rt][nc] = __builtin_amdgcn_mfma_f32_16x16x32_bf16(
                        af[rt], bf[nc], acc[rt][nc], 0, 0, 0);
        }

        // ---- epilogue: silu(z+b1) dot W2 over this wave's 64 cols ----
        float part[2][4];
#pragma unroll
        for (int rt = 0; rt < 2; ++rt)
#pragma unroll
            for (int rr = 0; rr < 4; ++rr) {
                float sv = 0.f;
#pragma unroll
                for (int nc = 0; nc < 4; ++nc) {
                    float z = acc[rt][nc][rr] + b1v[nc];
                    float h = z / (1.f + __expf(-z));
                    sv += h * w2v[nc];
                }
                part[rt][rr] = sv;
            }
#pragma unroll
        for (int off = 1; off < 16; off <<= 1)
#pragma unroll
            for (int rt = 0; rt < 2; ++rt)
#pragma unroll
                for (int rr = 0; rr < 4; ++rr)
                    part[rt][rr] += __shfl_xor(part[rt][rr], off, 16);
        if (l15 == 0) {
#pragma unroll
            for (int rt = 0; rt < 2; ++rt)
#pragma unroll
                for (int rr = 0; rr < 4; ++rr)
                    s_red[cur][wq][rt * 16 + g * 4 + rr] = part[rt][rr];
        }

        // ---- cvt + ds_write prefetched tile into other buffer ----
        // (counted vmcnt wait on r0/r1: HBM latency hidden under compute)
        if (more) CVTW(cur ^ 1, r0, r1);

        asm volatile("s_waitcnt lgkmcnt(0)" ::: "memory");   // my LDS ops done
        __builtin_amdgcn_s_barrier();                         // NO vmcnt drain
        asm volatile("" ::: "memory");
        __builtin_amdgcn_sched_barrier(0);

        // ---- scatter tile t (atomics fire-and-forget, never waited) ----
        if (nd >= 0) {
            float sv = s_red[cur][0][tid] + s_red[cur][1][tid]
                     + s_red[cur][2][tid] + s_red[cur][3][tid] + b2v;
            atomicAdd(&out[(long)nd * 3 + 0], sv * vx);
            atomicAdd(&out[(long)nd * 3 + 1], sv * vy);
            atomicAdd(&out[(long)nd * 3 + 2], sv * vz);
        }
    }
}

extern "C" void kernel_launch(void* const* d_in, const int* in_sizes, int n_in,
                              void* d_out, int out_size, void* d_ws, size_t ws_size,
                              hipStream_t stream) {
    const float* forces = (const float*)d_in[0];
    const float* V_st   = (const float*)d_in[1];
    const float* W1     = (const float*)d_in[2];
    const float* b1     = (const float*)d_in[3];
    const float* W2     = (const float*)d_in[4];
    const float* b2     = (const float*)d_in[5];
    const int*   idx    = (const int*)d_in[6];
    const int E = in_sizes[6];

    u16* W1F = (u16*)d_ws;  // 256*256*2 = 131072 B

    prep_kernel<<<D + 128, 256, 0, stream>>>(W1, W1F, (float*)d_out, out_size);
    head_kernel<<<NBLK, NT, 0, stream>>>(forces, V_st, W1F, b1, W2, b2, idx,
                                         (float*)d_out, E);
}

// Round 24
// 422.922 us; speedup vs baseline: 1.7923x; 1.7923x over previous
//
#include <hip/hip_runtime.h>
#include <hip/hip_bf16.h>

typedef __attribute__((ext_vector_type(8))) short short8;
typedef __attribute__((ext_vector_type(4))) float floatx4;
typedef unsigned short u16;

#define D 256
#define BM 64          // rows per tile
#define TILES 4        // tiles per block
#define NT 256

__device__ __forceinline__ short f2bf(float f) {
    return __builtin_bit_cast(short, __float2bfloat16(f));
}

// prep: blocks [0,256): W1 fp32 [k][n] -> W1F bf16 MFMA-fragment-major:
// W1F[((k0t*16+nt)*64+lane)*8+j] = W1[k0t*32+(lane>>4)*8+j][nt*16+(lane&15)]
//       blocks [256,384): zero d_out.
__global__ void prep_kernel(const float* __restrict__ W1, u16* __restrict__ W1F,
                            float* __restrict__ out, int outn) {
    const int b = blockIdx.x;
    if (b < D) {
        const int k = b, n = threadIdx.x;
        const int k0t = k >> 5, g = (k >> 3) & 3, j = k & 7;
        const int nt = n >> 4, l15 = n & 15;
        W1F[(long)((((k0t << 4) + nt) << 6) + (g << 4) + l15) * 8 + j] = (u16)f2bf(W1[k * D + n]);
    } else {
        int i = (b - D) * 256 + threadIdx.x;
        const int stride = (gridDim.x - D) * 256;
        for (; i < outn; i += stride) out[i] = 0.f;
    }
}

struct R8 { floatx4 f0, f1; };

// Non-persistent 4-tile block with rolling double-buffer under PLAIN
// __syncthreads. Interval = {issue burst(t+1) [pinned]; compute(t) from LDS;
// epilogue->s_red[t]; cvt+write(t+1); sync}. By each barrier the burst has
// already been consumed by cvt -> the implicit vmcnt(0) drain is a no-op and
// the burst's HBM service overlapped compute(t). Non-persistent straight-line
// code avoids the hipcc persistent-loop 64-VGPR spill pathology (R16/R23).
__launch_bounds__(NT, 2)
__global__ void head_kernel(const float* __restrict__ forces,
                            const float* __restrict__ V_st,
                            const u16*   __restrict__ W1F,
                            const float* __restrict__ b1,
                            const float* __restrict__ W2,
                            const float* __restrict__ b2,
                            const int*   __restrict__ idx_t,
                            float* __restrict__ out,
                            int E) {
    // A frag f = k0t*4 + (row>>4); in-frag slot ((g<<4)|(row&15))*8 (R11/R19 proven)
    __shared__ u16 Albs[2][32 * 512];      // 2 x 32 KiB double buffer
    __shared__ float s_red[TILES][4][BM];  // 4 KiB [tile][wq][row]

    const int tid  = threadIdx.x;
    const int lane = tid & 63;
    const int wq   = tid >> 6;        // 0..3: col quarter owned by this wave
    const int l15  = lane & 15;
    const int g    = lane >> 4;       // 0..3

    const long blk0 = (long)blockIdx.x * (BM * TILES);   // 256 edges; E%256==0

    // ---- scatter-operand prefetch: thread <-> edge blk0+tid (consumed at end)
    const long my_e = blk0 + tid;
    const float mvx = V_st[my_e * 3 + 0];
    const float mvy = V_st[my_e * 3 + 1];
    const float mvz = V_st[my_e * 3 + 2];
    const int  mnd  = idx_t[my_e];

    // per-wave epilogue constants
    float b1v[4], w2v[4];
#pragma unroll
    for (int nc = 0; nc < 4; ++nc) {
        int n = wq * 64 + nc * 16 + l15;
        b1v[nc] = b1[n];
        w2v[nc] = W2[n];
    }
    const float b2v = b2[0];

    // staging geometry (R19's proven conflict-free layout)
    const int arow  = tid >> 2;       // 0..63
    const int agg   = tid & 3;
    const int aslot = ((agg << 4) | (arow & 15)) * 8;
    const int art   = arow >> 4;

    auto BURST = [&](int t, R8* r) {
        const float* abase = forces + (blk0 + t * BM + arow) * (long)D + agg * 8;
#pragma unroll
        for (int k0t = 0; k0t < 8; ++k0t) {
            r[k0t].f0 = *(const floatx4*)(abase + k0t * 32);
            r[k0t].f1 = *(const floatx4*)(abase + k0t * 32 + 4);
        }
    };
    auto CVTW = [&](int buf, const R8* r) {
#pragma unroll
        for (int k0t = 0; k0t < 8; ++k0t) {
            short8 a;
#pragma unroll
            for (int j = 0; j < 4; ++j) { a[j] = f2bf(r[k0t].f0[j]); a[4 + j] = f2bf(r[k0t].f1[j]); }
            *(short8*)&Albs[buf][(k0t * 4 + art) * 512 + aslot] = a;
        }
    };
    auto COMPUTE = [&](int buf, int t) {
        floatx4 acc[4][4];
#pragma unroll
        for (int rt = 0; rt < 4; ++rt)
#pragma unroll
            for (int nc = 0; nc < 4; ++nc)
                acc[rt][nc] = (floatx4){0.f, 0.f, 0.f, 0.f};
#pragma unroll
        for (int k0t = 0; k0t < 8; ++k0t) {
            short8 bf[4], af[4];
#pragma unroll
            for (int nc = 0; nc < 4; ++nc)
                bf[nc] = *(const short8*)(W1F + (long)((k0t * 16 + wq * 4 + nc) * 64 + lane) * 8);
#pragma unroll
            for (int rt = 0; rt < 4; ++rt)
                af[rt] = *(const short8*)&Albs[buf][(k0t * 4 + rt) * 512 + lane * 8];
#pragma unroll
            for (int rt = 0; rt < 4; ++rt)
#pragma unroll
                for (int nc = 0; nc < 4; ++nc)
                    acc[rt][nc] = __builtin_amdgcn_mfma_f32_16x16x32_bf16(
                        af[rt], bf[nc], acc[rt][nc], 0, 0, 0);
        }
        // epilogue: silu(z+b1) dot W2 -> 16-lane reduce -> s_red[t]
        float part[4][4];
#pragma unroll
        for (int rt = 0; rt < 4; ++rt)
#pragma unroll
            for (int rr = 0; rr < 4; ++rr) {
                float sv = 0.f;
#pragma unroll
                for (int nc = 0; nc < 4; ++nc) {
                    float z = acc[rt][nc][rr] + b1v[nc];
                    float h = z / (1.f + __expf(-z));
                    sv += h * w2v[nc];
                }
                part[rt][rr] = sv;
            }
#pragma unroll
        for (int off = 1; off < 16; off <<= 1)
#pragma unroll
            for (int rt = 0; rt < 4; ++rt)
#pragma unroll
                for (int rr = 0; rr < 4; ++rr)
                    part[rt][rr] += __shfl_xor(part[rt][rr], off, 16);
        if (l15 == 0) {
#pragma unroll
            for (int rt = 0; rt < 4; ++rt)
#pragma unroll
                for (int rr = 0; rr < 4; ++rr)
                    s_red[t][wq][rt * 16 + g * 4 + rr] = part[rt][rr];
        }
    };

    // ---- interval 0: stage tile 0 ----
    {
        R8 r[8];
        BURST(0, r);
        CVTW(0, r);
    }
    __syncthreads();

    // ---- intervals 1..3: issue(t) || compute(t-1), then cvt+write(t) ----
#pragma unroll
    for (int t = 1; t < TILES; ++t) {
        R8 r[8];
        BURST(t, r);                          // burst issued FIRST
        __builtin_amdgcn_sched_barrier(0);    // pin: loads may not sink below
        COMPUTE((t - 1) & 1, t - 1);          // overlaps the burst's HBM service
        CVTW(t & 1, r);                       // counted vmcnt wait (already arrived)
        __syncthreads();                      // drain = no-op; publishes Albs+s_red
    }

    // ---- interval 4: compute last tile ----
    COMPUTE((TILES - 1) & 1, TILES - 1);
    __syncthreads();

    // ---- scatter: thread tid owns edge blk0+tid (tile=tid>>6, row=tid&63) ----
    {
        const int tt = tid >> 6, row = tid & 63;
        float sv = s_red[tt][0][row] + s_red[tt][1][row]
                 + s_red[tt][2][row] + s_red[tt][3][row] + b2v;
        atomicAdd(&out[(long)mnd * 3 + 0], sv * mvx);
        atomicAdd(&out[(long)mnd * 3 + 1], sv * mvy);
        atomicAdd(&out[(long)mnd * 3 + 2], sv * mvz);
    }
}

extern "C" void kernel_launch(void* const* d_in, const int* in_sizes, int n_in,
                              void* d_out, int out_size, void* d_ws, size_t ws_size,
                              hipStream_t stream) {
    const float* forces = (const float*)d_in[0];
    const float* V_st   = (const float*)d_in[1];
    const float* W1     = (const float*)d_in[2];
    const float* b1     = (const float*)d_in[3];
    const float* W2     = (const float*)d_in[4];
    const float* b2     = (const float*)d_in[5];
    const int*   idx    = (const int*)d_in[6];
    const int E = in_sizes[6];

    u16* W1F = (u16*)d_ws;  // 256*256*2 = 131072 B

    prep_kernel<<<D + 128, 256, 0, stream>>>(W1, W1F, (float*)d_out, out_size);
    const int grid = E / (BM * TILES);   // 3125
    head_kernel<<<grid, NT, 0, stream>>>(forces, V_st, W1F, b1, W2, b2, idx,
                                         (float*)d_out, E);
}

// Round 25
// 366.362 us; speedup vs baseline: 2.0690x; 1.1544x over previous
//
#include <hip/hip_runtime.h>
#include <hip/hip_bf16.h>

typedef __attribute__((ext_vector_type(8))) short short8;
typedef __attribute__((ext_vector_type(4))) float floatx4;
typedef unsigned short u16;

#define D 256
#define BM 32
#define NT 512

__device__ __forceinline__ short f2bf(float f) {
    return __builtin_bit_cast(short, __float2bfloat16(f));
}

// prep: blocks [0,256): W1 fp32 [k][n] -> W1F bf16 MFMA-fragment-major:
// W1F[((k0t*16+nt)*64+lane)*8+j] = W1[k0t*32+(lane>>4)*8+j][nt*16+(lane&15)]
//       blocks [256,384): zero d_out.
__global__ void prep_kernel(const float* __restrict__ W1, u16* __restrict__ W1F,
                            float* __restrict__ out, int outn) {
    const int b = blockIdx.x;
    if (b < D) {
        const int k = b, n = threadIdx.x;
        const int k0t = k >> 5, g = (k >> 3) & 3, j = k & 7;
        const int nt = n >> 4, l15 = n & 15;
        W1F[(long)((((k0t << 4) + nt) << 6) + (g << 4) + l15) * 8 + j] = (u16)f2bf(W1[k * D + n]);
    } else {
        int i = (b - D) * 256 + threadIdx.x;
        const int stride = (gridDim.x - D) * 256;
        for (; i < outn; i += stride) out[i] = 0.f;
    }
}

#define GLOAD_LDS(g, l) __builtin_amdgcn_global_load_lds( \
    (const __attribute__((address_space(1))) unsigned int*)(g), \
    (__attribute__((address_space(3))) unsigned int*)(l), 16, 0, 0)

// Max-occupancy head: 32 waves/CU (4 blocks x 8 waves at <=64 VGPR).
// Zero-register staging: global_load_lds pulls the fp32 A-tile straight to
// LDS (no dest VGPRs). Both-sides XOR chunk swizzle (rule 21): write side
// sources global chunk lane^(r&7) (still one coalesced 1KB row per instr);
// read side applies the same XOR -> bank = (r&7)*4 -> max 2-way = free.
// Wave tile 16x64 -> acc 16 VGPR; fp32->bf16 cvt inline at LDS-read.
__launch_bounds__(NT, 8)
__global__ void head_kernel(const float* __restrict__ forces,
                            const float* __restrict__ V_st,
                            const u16*   __restrict__ W1F,
                            const float* __restrict__ b1,
                            const float* __restrict__ W2,
                            const float* __restrict__ b2,
                            const int*   __restrict__ idx_t,
                            float* __restrict__ out,
                            int E) {
    __shared__ float Af[BM * D];        // 32 KiB fp32, chunk-XOR swizzled
    __shared__ float s_red[2][4][16];   // 512 B [row-half][wq][row-in-half]

    const int tid  = threadIdx.x;
    const int lane = tid & 63;
    const int w    = tid >> 6;      // 0..7
    const int rg   = w >> 2;        // row half (16 rows)
    const int wq   = w & 3;         // col quarter
    const int l15  = lane & 15;
    const int g    = lane >> 4;     // 0..3

    const long row0 = (long)blockIdx.x * BM;   // E%32==0: no tail

    // ---- scatter-operand prefetch ----
    float vx = 0.f, vy = 0.f, vz = 0.f;
    int nd = -1;
    if (tid < BM) {
        long e = row0 + tid;
        vx = V_st[e * 3 + 0]; vy = V_st[e * 3 + 1]; vz = V_st[e * 3 + 2];
        nd = idx_t[e];
    }

    // ---- stage A via global_load_lds: wave w stages rows [w*4, w*4+4) ----
    // LDS[r][p] = G[r][p ^ (r&7)] in 16B chunks; per-instr global span = 1KB row.
#pragma unroll
    for (int j = 0; j < 4; ++j) {
        int r = w * 4 + j;
        const float* src = forces + (row0 + r) * (long)D + ((lane ^ (r & 7)) << 2);
        GLOAD_LDS(src, &Af[r * D]);
    }
    __syncthreads();   // drains the stage (needed before reads anyway)

    // ---- MFMA: wave tile = rows [rg*16,+16) x cols [wq*64,+64) ----
    floatx4 acc[4];
#pragma unroll
    for (int nc = 0; nc < 4; ++nc)
        acc[nc] = (floatx4){0.f, 0.f, 0.f, 0.f};

    const int r  = rg * 16 + l15;      // this lane's A row
    const int q  = r & 7;              // read-side swizzle key
    const float* arp = &Af[r * D];

#pragma unroll
    for (int k0t = 0; k0t < 8; ++k0t) {
        const int cu = k0t * 8 + g * 2;    // 16B chunk of k = g*8..
        floatx4 f0 = *(const floatx4*)(arp + ((cu ^ q) << 2));
        floatx4 f1 = *(const floatx4*)(arp + (((cu + 1) ^ q) << 2));
        short8 af;
#pragma unroll
        for (int j = 0; j < 4; ++j) { af[j] = f2bf(f0[j]); af[4 + j] = f2bf(f1[j]); }
#pragma unroll
        for (int nc = 0; nc < 4; ++nc) {
            short8 bf = *(const short8*)(W1F +
                (long)((k0t * 16 + wq * 4 + nc) * 64 + lane) * 8);
            acc[nc] = __builtin_amdgcn_mfma_f32_16x16x32_bf16(af, bf, acc[nc], 0, 0, 0);
        }
    }

    // ---- epilogue: silu(z+b1) dot W2 over this wave's 64 cols ----
    float b1v[4], w2v[4];
#pragma unroll
    for (int nc = 0; nc < 4; ++nc) {
        int n = wq * 64 + nc * 16 + l15;
        b1v[nc] = b1[n];
        w2v[nc] = W2[n];
    }
    float part[4];   // C/D: col=l15, frag row=g*4+rr (m89); abs row=rg*16+g*4+rr
#pragma unroll
    for (int rr = 0; rr < 4; ++rr) {
        float sv = 0.f;
#pragma unroll
        for (int nc = 0; nc < 4; ++nc) {
            float z = acc[nc][rr] + b1v[nc];
            float h = z / (1.f + __expf(-z));
            sv += h * w2v[nc];
        }
        part[rr] = sv;
    }
#pragma unroll
    for (int off = 1; off < 16; off <<= 1)
#pragma unroll
        for (int rr = 0; rr < 4; ++rr)
            part[rr] += __shfl_xor(part[rr], off, 16);

    if (l15 == 0) {
#pragma unroll
        for (int rr = 0; rr < 4; ++rr)
            s_red[rg][wq][g * 4 + rr] = part[rr];
    }
    __syncthreads();

    // ---- scalar + scatter: thread tid<32 owns row tid ----
    if (nd >= 0) {
        const int rh = tid >> 4, rin = tid & 15;
        float sv = s_red[rh][0][rin] + s_red[rh][1][rin]
                 + s_red[rh][2][rin] + s_red[rh][3][rin] + b2[0];
        atomicAdd(&out[(long)nd * 3 + 0], sv * vx);
        atomicAdd(&out[(long)nd * 3 + 1], sv * vy);
        atomicAdd(&out[(long)nd * 3 + 2], sv * vz);
    }
}

extern "C" void kernel_launch(void* const* d_in, const int* in_sizes, int n_in,
                              void* d_out, int out_size, void* d_ws, size_t ws_size,
                              hipStream_t stream) {
    const float* forces = (const float*)d_in[0];
    const float* V_st   = (const float*)d_in[1];
    const float* W1     = (const float*)d_in[2];
    const float* b1     = (const float*)d_in[3];
    const float* W2     = (const float*)d_in[4];
    const float* b2     = (const float*)d_in[5];
    const int*   idx    = (const int*)d_in[6];
    const int E = in_sizes[6];

    u16* W1F = (u16*)d_ws;  // 256*256*2 = 131072 B

    prep_kernel<<<D + 128, 256, 0, stream>>>(W1, W1F, (float*)d_out, out_size);
    const int grid = E / BM;   // 25000
    head_kernel<<<grid, NT, 0, stream>>>(forces, V_st, W1F, b1, W2, b2, idx,
                                         (float*)d_out, E);
}

// Round 26
// 280.201 us; speedup vs baseline: 2.7053x; 1.3075x over previous
//
#include <hip/hip_runtime.h>
#include <hip/hip_bf16.h>

typedef __attribute__((ext_vector_type(8))) short short8;
typedef __attribute__((ext_vector_type(4))) float floatx4;
typedef unsigned short u16;

#define D 256
#define BM 64
#define NT 256

__device__ __forceinline__ short f2bf(float f) {
    return __builtin_bit_cast(short, __float2bfloat16(f));
}

// prep: blocks [0,256): W1 fp32 [k][n] -> W1F bf16 MFMA-fragment-major:
// W1F[((k0t*16+nt)*64+lane)*8+j] = W1[k0t*32+(lane>>4)*8+j][nt*16+(lane&15)]
//       blocks [256,384): zero d_out.
__global__ void prep_kernel(const float* __restrict__ W1, u16* __restrict__ W1F,
                            float* __restrict__ out, int outn) {
    const int b = blockIdx.x;
    if (b < D) {
        const int k = b, n = threadIdx.x;
        const int k0t = k >> 5, g = (k >> 3) & 3, j = k & 7;
        const int nt = n >> 4, l15 = n & 15;
        W1F[(long)((((k0t << 4) + nt) << 6) + (g << 4) + l15) * 8 + j] = (u16)f2bf(W1[k * D + n]);
    } else {
        int i = (b - D) * 256 + threadIdx.x;
        const int stride = (gridDim.x - D) * 256;
        for (; i < outn; i += stride) out[i] = 0.f;
    }
}

struct R8 { floatx4 f0, f1; };

// FINAL (R19 structure, session best 280.6us): 64-edge tile, 4 waves,
// 33 KiB LDS -> 4 blocks/CU. Burst staging (16 loads in flight), A
// fragment-major in LDS (all ds accesses contiguous 1 KiB wave
// transactions, conflict-free). Each wave owns all 64 rows x one 64-col
// quarter (2 KB/row B-traffic from L2-hot W1F). Two barriers per block;
// scatter operands prefetched at block top; atomics fire-and-forget.
// Session ladder: 527 -> 299 (staged+prefragmented B) -> 282 (4 blk/CU)
// -> 280.6 (tall waves). Eleven pipelining variants (dbuf, producer/
// consumer, raw s_barrier, rolling dbuf, barrier-free dataflow) all
// regressed: hipcc drains vmcnt(0) at __syncthreads and refuses burst
// register allocation in persistent loops (VGPR_Count=64 pathology).
__launch_bounds__(NT, 4)
__global__ void head_kernel(const float* __restrict__ forces,
                            const float* __restrict__ V_st,
                            const u16*   __restrict__ W1F,
                            const float* __restrict__ b1,
                            const float* __restrict__ W2,
                            const float* __restrict__ b2,
                            const int*   __restrict__ idx_t,
                            float* __restrict__ out,
                            int E) {
    // A frag f = k0t*4 + (row>>4); in-frag slot ((g<<4)|(row&15))*8 + j shorts
    __shared__ u16 Albs[32 * 512];    // 32 KiB
    __shared__ float s_red[4][BM];    // 1 KiB

    const int tid  = threadIdx.x;
    const int lane = tid & 63;
    const int wq   = tid >> 6;        // 0..3: col quarter owned by this wave
    const int l15  = lane & 15;
    const int g    = lane >> 4;       // 0..3

    const long row0 = (long)blockIdx.x * BM;   // E%64==0: no tail

    // ---- scatter-operand prefetch (in flight across the whole block) ----
    float vx = 0.f, vy = 0.f, vz = 0.f;
    int node = -1;
    if (tid < BM) {
        long e = row0 + tid;
        vx = V_st[e * 3 + 0]; vy = V_st[e * 3 + 1]; vz = V_st[e * 3 + 2];
        node = idx_t[e];
    }

    // ---- stage A: burst 16 loads (thread = arow=tid>>2, agg=tid&3) ----
    const int arow = tid >> 2;        // 0..63
    const int agg  = tid & 3;
    const float* abase = forces + (row0 + arow) * D + agg * 8;

    R8 r[8];
#pragma unroll
    for (int k0t = 0; k0t < 8; ++k0t) {
        r[k0t].f0 = *(const floatx4*)(abase + k0t * 32);
        r[k0t].f1 = *(const floatx4*)(abase + k0t * 32 + 4);
    }
    const int aslot = ((agg << 4) | (arow & 15)) * 8;
    const int art   = arow >> 4;
#pragma unroll
    for (int k0t = 0; k0t < 8; ++k0t) {
        short8 a;
#pragma unroll
        for (int j = 0; j < 4; ++j) { a[j] = f2bf(r[k0t].f0[j]); a[4 + j] = f2bf(r[k0t].f1[j]); }
        *(short8*)&Albs[(k0t * 4 + art) * 512 + aslot] = a;
    }
    __syncthreads();

    // ---- MFMA: wave tile 64 rows x 64 cols = 4 rt x 4 nc fragments ----
    floatx4 acc[4][4];
#pragma unroll
    for (int rt = 0; rt < 4; ++rt)
#pragma unroll
        for (int nc = 0; nc < 4; ++nc)
            acc[rt][nc] = (floatx4){0.f, 0.f, 0.f, 0.f};

#pragma unroll
    for (int k0t = 0; k0t < 8; ++k0t) {
        short8 bf[4], af[4];
#pragma unroll
        for (int nc = 0; nc < 4; ++nc)
            bf[nc] = *(const short8*)(W1F + (long)((k0t * 16 + wq * 4 + nc) * 64 + lane) * 8);
#pragma unroll
        for (int rt = 0; rt < 4; ++rt)
            af[rt] = *(const short8*)&Albs[(k0t * 4 + rt) * 512 + lane * 8];
#pragma unroll
        for (int rt = 0; rt < 4; ++rt)
#pragma unroll
            for (int nc = 0; nc < 4; ++nc)
                acc[rt][nc] = __builtin_amdgcn_mfma_f32_16x16x32_bf16(
                    af[rt], bf[nc], acc[rt][nc], 0, 0, 0);
    }

    // ---- epilogue: silu(z+b1) dot W2 over this wave's 64 cols ----
    float b1v[4], w2v[4];
#pragma unroll
    for (int nc = 0; nc < 4; ++nc) {
        int n = wq * 64 + nc * 16 + l15;
        b1v[nc] = b1[n];
        w2v[nc] = W2[n];
    }
    float part[4][4];  // [rt][rr]; C/D: col=lane&15, row=(lane>>4)*4+reg (m89)
#pragma unroll
    for (int rt = 0; rt < 4; ++rt)
#pragma unroll
        for (int rr = 0; rr < 4; ++rr) {
            float sv = 0.f;
#pragma unroll
            for (int nc = 0; nc < 4; ++nc) {
                float z = acc[rt][nc][rr] + b1v[nc];
                float h = z / (1.f + __expf(-z));
                sv += h * w2v[nc];
            }
            part[rt][rr] = sv;
        }

#pragma unroll
    for (int off = 1; off < 16; off <<= 1)
#pragma unroll
        for (int rt = 0; rt < 4; ++rt)
#pragma unroll
            for (int rr = 0; rr < 4; ++rr)
                part[rt][rr] += __shfl_xor(part[rt][rr], off, 16);

    if (l15 == 0) {
#pragma unroll
        for (int rt = 0; rt < 4; ++rt)
#pragma unroll
            for (int rr = 0; rr < 4; ++rr)
                s_red[wq][rt * 16 + g * 4 + rr] = part[rt][rr];
    }
    __syncthreads();

    // ---- scalar + scatter (operands already in registers) ----
    if (node >= 0) {
        float sv = s_red[0][tid] + s_red[1][tid] + s_red[2][tid] + s_red[3][tid] + b2[0];
        atomicAdd(&out[(long)node * 3 + 0], sv * vx);
        atomicAdd(&out[(long)node * 3 + 1], sv * vy);
        atomicAdd(&out[(long)node * 3 + 2], sv * vz);
    }
}

extern "C" void kernel_launch(void* const* d_in, const int* in_sizes, int n_in,
                              void* d_out, int out_size, void* d_ws, size_t ws_size,
                              hipStream_t stream) {
    const float* forces = (const float*)d_in[0];
    const float* V_st   = (const float*)d_in[1];
    const float* W1     = (const float*)d_in[2];
    const float* b1     = (const float*)d_in[3];
    const float* W2     = (const float*)d_in[4];
    const float* b2     = (const float*)d_in[5];
    const int*   idx    = (const int*)d_in[6];
    const int E = in_sizes[6];

    u16* W1F = (u16*)d_ws;  // 256*256*2 = 131072 B

    prep_kernel<<<D + 128, 256, 0, stream>>>(W1, W1F, (float*)d_out, out_size);
    const int grid = E / BM;
    head_kernel<<<grid, NT, 0, stream>>>(forces, V_st, W1F, b1, W2, b2, idx,
                                         (float*)d_out, E);
}

// Round 27
// 276.432 us; speedup vs baseline: 2.7422x; 1.0136x over previous
//
#include <hip/hip_runtime.h>
#include <hip/hip_bf16.h>

typedef __attribute__((ext_vector_type(8))) short short8;
typedef __attribute__((ext_vector_type(4))) float floatx4;
typedef unsigned short u16;

#define D 256
#define BM 64
#define NT 256

__device__ __forceinline__ short f2bf(float f) {
    return __builtin_bit_cast(short, __float2bfloat16(f));
}

// prep: blocks [0,256): W1 fp32 [k][n] -> W1F bf16 MFMA-fragment-major:
// W1F[((k0t*16+nt)*64+lane)*8+j] = W1[k0t*32+(lane>>4)*8+j][nt*16+(lane&15)]
//       blocks [256,384): zero d_out.
__global__ void prep_kernel(const float* __restrict__ W1, u16* __restrict__ W1F,
                            float* __restrict__ out, int outn) {
    const int b = blockIdx.x;
    if (b < D) {
        const int k = b, n = threadIdx.x;
        const int k0t = k >> 5, g = (k >> 3) & 3, j = k & 7;
        const int nt = n >> 4, l15 = n & 15;
        W1F[(long)((((k0t << 4) + nt) << 6) + (g << 4) + l15) * 8 + j] = (u16)f2bf(W1[k * D + n]);
    } else {
        int i = (b - D) * 256 + threadIdx.x;
        const int stride = (gridDim.x - D) * 256;
        for (; i < outn; i += stride) out[i] = 0.f;
    }
}

struct R8 { floatx4 f0, f1; };

// R19 (session best 280.2us) + ONE change: sched_barrier(0) after the
// 16-load A-burst. Every time a head kernel WAS profiled (R16/R17/R23),
// hipcc had sunk each staging load next to its cvt (VGPR_Count 64-68) and
// serialized the stage into ~16 dependent ~900cy waits. R18 proved the
// fence fixes that (523->437 on the dataflow kernel). R19's burst was
// never verified -- this is the controlled A/B on the winning structure.
// Peak VGPR with the pinned burst ~105 < 128 -> still 4 blocks/CU.
__launch_bounds__(NT, 4)
__global__ void head_kernel(const float* __restrict__ forces,
                            const float* __restrict__ V_st,
                            const u16*   __restrict__ W1F,
                            const float* __restrict__ b1,
                            const float* __restrict__ W2,
                            const float* __restrict__ b2,
                            const int*   __restrict__ idx_t,
                            float* __restrict__ out,
                            int E) {
    // A frag f = k0t*4 + (row>>4); in-frag slot ((g<<4)|(row&15))*8 + j shorts
    __shared__ u16 Albs[32 * 512];    // 32 KiB
    __shared__ float s_red[4][BM];    // 1 KiB

    const int tid  = threadIdx.x;
    const int lane = tid & 63;
    const int wq   = tid >> 6;        // 0..3: col quarter owned by this wave
    const int l15  = lane & 15;
    const int g    = lane >> 4;       // 0..3

    const long row0 = (long)blockIdx.x * BM;   // E%64==0: no tail

    // ---- scatter-operand prefetch (in flight across the whole block) ----
    float vx = 0.f, vy = 0.f, vz = 0.f;
    int node = -1;
    if (tid < BM) {
        long e = row0 + tid;
        vx = V_st[e * 3 + 0]; vy = V_st[e * 3 + 1]; vz = V_st[e * 3 + 2];
        node = idx_t[e];
    }

    // ---- stage A: burst 16 loads (thread = arow=tid>>2, agg=tid&3) ----
    const int arow = tid >> 2;        // 0..63
    const int agg  = tid & 3;
    const float* abase = forces + (row0 + arow) * D + agg * 8;

    R8 r[8];
#pragma unroll
    for (int k0t = 0; k0t < 8; ++k0t) {
        r[k0t].f0 = *(const floatx4*)(abase + k0t * 32);
        r[k0t].f1 = *(const floatx4*)(abase + k0t * 32 + 4);
    }
    __builtin_amdgcn_sched_barrier(0);   // pin: all 16 loads issue BEFORE cvt
    const int aslot = ((agg << 4) | (arow & 15)) * 8;
    const int art   = arow >> 4;
#pragma unroll
    for (int k0t = 0; k0t < 8; ++k0t) {
        short8 a;
#pragma unroll
        for (int j = 0; j < 4; ++j) { a[j] = f2bf(r[k0t].f0[j]); a[4 + j] = f2bf(r[k0t].f1[j]); }
        *(short8*)&Albs[(k0t * 4 + art) * 512 + aslot] = a;
    }
    __syncthreads();

    // ---- MFMA: wave tile 64 rows x 64 cols = 4 rt x 4 nc fragments ----
    floatx4 acc[4][4];
#pragma unroll
    for (int rt = 0; rt < 4; ++rt)
#pragma unroll
        for (int nc = 0; nc < 4; ++nc)
            acc[rt][nc] = (floatx4){0.f, 0.f, 0.f, 0.f};

#pragma unroll
    for (int k0t = 0; k0t < 8; ++k0t) {
        short8 bf[4], af[4];
#pragma unroll
        for (int nc = 0; nc < 4; ++nc)
            bf[nc] = *(const short8*)(W1F + (long)((k0t * 16 + wq * 4 + nc) * 64 + lane) * 8);
#pragma unroll
        for (int rt = 0; rt < 4; ++rt)
            af[rt] = *(const short8*)&Albs[(k0t * 4 + rt) * 512 + lane * 8];
#pragma unroll
        for (int rt = 0; rt < 4; ++rt)
#pragma unroll
            for (int nc = 0; nc < 4; ++nc)
                acc[rt][nc] = __builtin_amdgcn_mfma_f32_16x16x32_bf16(
                    af[rt], bf[nc], acc[rt][nc], 0, 0, 0);
    }

    // ---- epilogue: silu(z+b1) dot W2 over this wave's 64 cols ----
    float b1v[4], w2v[4];
#pragma unroll
    for (int nc = 0; nc < 4; ++nc) {
        int n = wq * 64 + nc * 16 + l15;
        b1v[nc] = b1[n];
        w2v[nc] = W2[n];
    }
    float part[4][4];  // [rt][rr]; C/D: col=lane&15, row=(lane>>4)*4+reg (m89)
#pragma unroll
    for (int rt = 0; rt < 4; ++rt)
#pragma unroll
        for (int rr = 0; rr < 4; ++rr) {
            float sv = 0.f;
#pragma unroll
            for (int nc = 0; nc < 4; ++nc) {
                float z = acc[rt][nc][rr] + b1v[nc];
                float h = z / (1.f + __expf(-z));
                sv += h * w2v[nc];
            }
            part[rt][rr] = sv;
        }

#pragma unroll
    for (int off = 1; off < 16; off <<= 1)
#pragma unroll
        for (int rt = 0; rt < 4; ++rt)
#pragma unroll
            for (int rr = 0; rr < 4; ++rr)
                part[rt][rr] += __shfl_xor(part[rt][rr], off, 16);

    if (l15 == 0) {
#pragma unroll
        for (int rt = 0; rt < 4; ++rt)
#pragma unroll
            for (int rr = 0; rr < 4; ++rr)
                s_red[wq][rt * 16 + g * 4 + rr] = part[rt][rr];
    }
    __syncthreads();

    // ---- scalar + scatter (operands already in registers) ----
    if (node >= 0) {
        float sv = s_red[0][tid] + s_red[1][tid] + s_red[2][tid] + s_red[3][tid] + b2[0];
        atomicAdd(&out[(long)node * 3 + 0], sv * vx);
        atomicAdd(&out[(long)node * 3 + 1], sv * vy);
        atomicAdd(&out[(long)node * 3 + 2], sv * vz);
    }
}

extern "C" void kernel_launch(void* const* d_in, const int* in_sizes, int n_in,
                              void* d_out, int out_size, void* d_ws, size_t ws_size,
                              hipStream_t stream) {
    const float* forces = (const float*)d_in[0];
    const float* V_st   = (const float*)d_in[1];
    const float* W1     = (const float*)d_in[2];
    const float* b1     = (const float*)d_in[3];
    const float* W2     = (const float*)d_in[4];
    const float* b2     = (const float*)d_in[5];
    const int*   idx    = (const int*)d_in[6];
    const int E = in_sizes[6];

    u16* W1F = (u16*)d_ws;  // 256*256*2 = 131072 B

    prep_kernel<<<D + 128, 256, 0, stream>>>(W1, W1F, (float*)d_out, out_size);
    const int grid = E / BM;
    head_kernel<<<grid, NT, 0, stream>>>(forces, V_st, W1F, b1, W2, b2, idx,
                                         (float*)d_out, E);
}